// Round 8
// baseline (243.569 us; speedup 1.0000x reference)
//
#include <hip/hip_runtime.h>

#define SEQ 2048
#define BATCH 2
#define DM 1024
#define NH 16
#define DH 64

typedef __bf16 bf16;
typedef __bf16 bf16x8 __attribute__((ext_vector_type(8)));
typedef __bf16 bf16x4 __attribute__((ext_vector_type(4)));
typedef float f32x4 __attribute__((ext_vector_type(4)));

#define MFMA16(a, b, c) __builtin_amdgcn_mfma_f32_16x16x32_bf16((a), (b), (c), 0, 0, 0)

#if __has_builtin(__builtin_amdgcn_exp2f)
#define EXP2(x) __builtin_amdgcn_exp2f(x)
#else
#define EXP2(x) exp2f(x)
#endif

// Q scale folds 1/sqrt(64) and log2(e) so softmax uses bare v_exp_f32 (exp2)
#define QSCALE 0.18033688f

// async global->LDS, 16B per lane; LDS dest = wave-uniform base + lane*16
typedef __attribute__((address_space(3))) void lds_void;
typedef __attribute__((address_space(1))) void glb_void;
__device__ __forceinline__ void gld16(void* lds, const void* g) {
    __builtin_amdgcn_global_load_lds((const glb_void*)g, (lds_void*)lds, 16, 0, 0);
}

// Sense-reversal grid barrier in workspace (cnt, gen zeroed by hipMemsetAsync
// before launch). Grid(256)==CU count at 1 block/CU (128KB LDS) -> all blocks
// co-resident by construction. Drains vmcnt first so each phase's counted
// vmcnt FIFO accounting starts clean. Device-scope atomics (m20) + threadfence.
__device__ __forceinline__ void gridbar(int* cnt, int* gen, int nblk) {
    asm volatile("s_waitcnt vmcnt(0) lgkmcnt(0)" ::: "memory");
    __syncthreads();
    if (threadIdx.x == 0) {
        __threadfence();                      // release this block's writes
        int g = atomicAdd(gen, 0);            // read generation BEFORE arrive
        int old = atomicAdd(cnt, 1);
        if (old == nblk - 1) {
            atomicExch(cnt, 0);
            __threadfence();
            atomicAdd(gen, 1);                // release next generation
        } else {
            while (atomicAdd(gen, 0) == g) __builtin_amdgcn_s_sleep(2);
        }
        __threadfence();                      // acquire other blocks' writes
    }
    __syncthreads();
}

// ---------------------------------------------------------------------------
// MEGA (normal launch): 256 blocks x 512 threads, 128 KB LDS, 1 block/CU.
// P0 prep -> bar -> P1 qkv (R7 body, 192 tiles) -> bar ->
// P2 attn (R7 8-wave body x balanced pair qt={j,15-j}) -> bar -> P3 out.
// All MFMA K-accumulation orders identical to the R7-verified kernels.
// ---------------------------------------------------------------------------
__global__ __launch_bounds__(512, 1) void k_mega(
    const float* __restrict__ x,  const float* __restrict__ WQ,
    const float* __restrict__ WK, const float* __restrict__ WV,
    const float* __restrict__ WO, const float* __restrict__ bQ,
    const float* __restrict__ bK, const float* __restrict__ bV,
    const float* __restrict__ bO, float* __restrict__ out,
    bf16* __restrict__ xb, bf16* __restrict__ wT, bf16* __restrict__ woT,
    bf16* __restrict__ Qb, bf16* __restrict__ Kb, bf16* __restrict__ VTf,
    bf16* __restrict__ Zb, int* __restrict__ bar)
{
    __shared__ __align__(16) char sm[131072];
    int* bcnt = bar;
    int* bgen = bar + 1;
    int bid = blockIdx.x;
    int t = threadIdx.x;
    int lane = t & 63, w = t >> 6;
    int l15 = lane & 15, quad = lane >> 4;

    // ======================= P0: prep ======================================
    {
        // cast x -> bf16: 524288 groups of 8; 256 blk x 512 thr x 4 iters
        const float4* x4 = (const float4*)x;
        for (int i = 0; i < 4; i++) {
            int g = bid * 2048 + i * 512 + t;
            float4 a = x4[2 * g];
            float4 b = x4[2 * g + 1];
            bf16x8 o;
            o[0] = (bf16)a.x; o[1] = (bf16)a.y; o[2] = (bf16)a.z; o[3] = (bf16)a.w;
            o[4] = (bf16)b.x; o[5] = (bf16)b.y; o[6] = (bf16)b.z; o[7] = (bf16)b.w;
            *(bf16x8*)(xb + 8 * g) = o;
        }
        // transposes: 1024 64x64 units (768 W_qkv + 256 W_O); 4 units/block
        bf16* T = (bf16*)sm;
        for (int i = 0; i < 4; i++) {
            int u = bid * 4 + i;               // uniform per block
            __syncthreads();                   // T reuse guard
            if (u < 768) {
                int kt = u & 15, ph = u >> 4;
                int p = ph >> 4, h = ph & 15;
                const float* Wp = (p == 0) ? WQ : (p == 1) ? WK : WV;
                const float* src = Wp + ((size_t)h * DM + (size_t)kt * 64) * DH;
                for (int ii = 0; ii < 2; ii++) {
                    int c = t + 512 * ii;
                    int r = c >> 4;
                    int col = (c & 15) * 4;
                    float4 v = *(const float4*)&src[r * 64 + col];
                    T[(col + 0) * 65 + r] = (bf16)v.x;
                    T[(col + 1) * 65 + r] = (bf16)v.y;
                    T[(col + 2) * 65 + r] = (bf16)v.z;
                    T[(col + 3) * 65 + r] = (bf16)v.w;
                }
                __syncthreads();
                bf16* dst = wT + (size_t)ph * 64 * DM + (size_t)kt * 64;
                int e = t >> 3;
                int k0 = (t & 7) * 8;
                bf16x8 o;
                for (int j = 0; j < 8; j++) o[j] = T[e * 65 + k0 + j];
                *(bf16x8*)&dst[(size_t)e * DM + k0] = o;
            } else {
                int id2 = u - 768;
                int ht = id2 & 15, dt = id2 >> 4;
                for (int ii = 0; ii < 2; ii++) {
                    int c = t + 512 * ii;
                    int r = c >> 4;
                    int col = (c & 15) * 4;
                    float4 v = *(const float4*)&WO[((size_t)(ht * 64 + r)) * DM + dt * 64 + col];
                    T[(col + 0) * 65 + r] = (bf16)v.x;
                    T[(col + 1) * 65 + r] = (bf16)v.y;
                    T[(col + 2) * 65 + r] = (bf16)v.z;
                    T[(col + 3) * 65 + r] = (bf16)v.w;
                }
                __syncthreads();
                int d = t >> 3;
                int h0 = (t & 7) * 8;
                bf16x8 o;
                for (int j = 0; j < 8; j++) o[j] = T[d * 65 + h0 + j];
                *(bf16x8*)&woT[((size_t)(dt * 64 + d)) * DM + ht * 64 + h0] = o;
            }
        }
    }
    gridbar(bcnt, bgen, 256);

    // ======================= P1: qkv (R7 body; 192 tiles) ==================
    if (bid < 192) {
        int mt = bid & 15, nt = (bid >> 4) & 3, p = bid >> 6;
        int wr = w >> 2, wc = w & 3;               // 2M x 4N wave grid
        int m0 = mt * 256, n0 = nt * 256;

        int P0 = t * 16;
        int L0 = P0 ^ (((P0 >> 7) & 3) << 4);
        int row0 = L0 >> 6, kc0 = (L0 >> 4) & 3;
        int P1 = 8192 + t * 16;
        int L1 = P1 ^ (((P1 >> 7) & 3) << 4);
        int row1 = L1 >> 6, kc1 = (L1 >> 4) & 3;
        const bf16* gA0 = xb + (size_t)(m0 + row0) * DM + kc0 * 8;
        const bf16* gA1 = xb + (size_t)(m0 + row1) * DM + kc1 * 8;
        const bf16* gB0 = wT + (size_t)(p * 1024 + n0 + row0) * DM + kc0 * 8;
        const bf16* gB1 = wT + (size_t)(p * 1024 + n0 + row1) * DM + kc1 * 8;

        auto stage = [&](int ts, bool bsel) {
            char* sb = sm + (ts & 3) * 32768;
            int ko = ts * 32;
            if (!bsel) {
                gld16(sb + w * 1024, gA0 + ko);
                gld16(sb + 8192 + w * 1024, gA1 + ko);
            } else {
                gld16(sb + 16384 + w * 1024, gB0 + ko);
                gld16(sb + 16384 + 8192 + w * 1024, gB1 + ko);
            }
        };

        int aoff[8], boff[4];
#pragma unroll
        for (int mi = 0; mi < 8; mi++) {
            int row = wr * 128 + mi * 16 + l15;
            aoff[mi] = row * 64 + ((quad ^ ((row >> 1) & 3)) << 4);
        }
#pragma unroll
        for (int ni = 0; ni < 4; ni++) {
            int row = wc * 64 + ni * 16 + l15;
            boff[ni] = 16384 + row * 64 + ((quad ^ ((row >> 1) & 3)) << 4);
        }

        const f32x4 z4 = {0.f, 0.f, 0.f, 0.f};
        f32x4 acc[8][4];
#pragma unroll
        for (int mi = 0; mi < 8; mi++)
#pragma unroll
            for (int ni = 0; ni < 4; ni++) acc[mi][ni] = z4;

        auto kstep = [&](int tt, bool st) {
            const char* sb = sm + (tt & 3) * 32768;
            bf16x8 bfr[4], afr[4];
#pragma unroll
            for (int ni = 0; ni < 4; ni++) bfr[ni] = *(const bf16x8*)(sb + boff[ni]);
#pragma unroll
            for (int mi = 0; mi < 4; mi++) afr[mi] = *(const bf16x8*)(sb + aoff[mi]);
            if (st) stage(tt + 3, false);
            __builtin_amdgcn_s_setprio(1);
#pragma unroll
            for (int mi = 0; mi < 4; mi++)
#pragma unroll
                for (int ni = 0; ni < 4; ni++)
                    acc[mi][ni] = MFMA16(afr[mi], bfr[ni], acc[mi][ni]);
            __builtin_amdgcn_s_setprio(0);
            bf16x8 afr2[4];
#pragma unroll
            for (int mi = 0; mi < 4; mi++) afr2[mi] = *(const bf16x8*)(sb + aoff[4 + mi]);
            if (st) stage(tt + 3, true);
            __builtin_amdgcn_s_setprio(1);
#pragma unroll
            for (int mi = 0; mi < 4; mi++)
#pragma unroll
                for (int ni = 0; ni < 4; ni++)
                    acc[4 + mi][ni] = MFMA16(afr2[mi], bfr[ni], acc[4 + mi][ni]);
            __builtin_amdgcn_s_setprio(0);
        };

        stage(0, false); stage(0, true);
        stage(1, false); stage(1, true);
        stage(2, false); stage(2, true);

#pragma unroll 1
        for (int tt = 0; tt < 29; tt++) {
            asm volatile("s_waitcnt vmcnt(8)\n\ts_barrier" ::: "memory");
            __builtin_amdgcn_sched_barrier(0);
            kstep(tt, true);
        }
        asm volatile("s_waitcnt vmcnt(8)\n\ts_barrier" ::: "memory");
        __builtin_amdgcn_sched_barrier(0);
        kstep(29, false);
        asm volatile("s_waitcnt vmcnt(4)\n\ts_barrier" ::: "memory");
        __builtin_amdgcn_sched_barrier(0);
        kstep(30, false);
        asm volatile("s_waitcnt vmcnt(0)\n\ts_barrier" ::: "memory");
        __builtin_amdgcn_sched_barrier(0);
        kstep(31, false);

        int b = m0 >> 11;
        if (p < 2) {
            const float* bias = (p == 0) ? bQ : bK;
            bf16* dst = (p == 0) ? Qb : Kb;
            float scale = (p == 0) ? QSCALE : 1.0f;
#pragma unroll
            for (int ni = 0; ni < 4; ni++) {
                int he = n0 + wc * 64 + ni * 16 + l15;
                int h = he >> 6, e = he & 63;
                float bia = bias[he];
                size_t rb = (size_t)(b * NH + h) * SEQ * DH + e;
#pragma unroll
                for (int mi = 0; mi < 8; mi++)
#pragma unroll
                    for (int r = 0; r < 4; r++) {
                        int s = ((m0 + wr * 128 + mi * 16 + quad * 4 + r) & 2047);
                        dst[rb + (size_t)s * DH] = (bf16)((acc[mi][ni][r] + bia) * scale);
                    }
            }
        } else {
#pragma unroll
            for (int ni = 0; ni < 4; ni++) {
                int he = n0 + wc * 64 + ni * 16 + l15;
                int h = he >> 6;
                float bia = bV[he];
#pragma unroll
                for (int mi = 0; mi < 8; mi++) {
                    int kvl = (mt & 7) * 256 + wr * 128 + mi * 16;
                    int kt = kvl >> 7;
                    int f = (mi >> 1) * 4 + ni;
                    size_t base = (((size_t)(b * NH + h) * 16 + kt) * 16 + f) * 512
                                  + (size_t)((quad << 4) | l15) * 8 + (mi & 1) * 4;
                    bf16x4 o;
#pragma unroll
                    for (int r = 0; r < 4; r++) o[r] = (bf16)(acc[mi][ni][r] + bia);
                    *(bf16x4*)&VTf[base] = o;
                }
            }
        }
    }
    gridbar(bcnt, bgen, 256);

    // ======================= P2: attn (R7 body x balanced pair) ============
    {
        bf16 (*Ks)[16 * 512] = (bf16 (*)[16 * 512])sm;        // 32 KB
        bf16* Vs = (bf16*)(sm + 32768);                       // 16 KB
        int bh = bid >> 3;                // 0..31
        int jj = bid & 7;                 // 0..7; passes qt=jj and qt=15-jj
        int h = bh & 15, b = bh >> 4;
        const bf16* qbase = Qb + (size_t)bh * SEQ * DH;
        const bf16* kbase = Kb + (size_t)bh * SEQ * DH;
        const bf16* vfrag = VTf + (size_t)bh * 16 * 8192;

        for (int pass = 0; pass < 2; pass++) {
            int qt = (pass == 0) ? jj : 15 - jj;
            __syncthreads();   // prev pass's LDS reads retired before restage

            int qr0 = qt * 128 + w * 16;
            bf16x8 aq[2];
            for (int ks = 0; ks < 2; ks++)
                aq[ks] = *(const bf16x8*)&qbase[(size_t)(qr0 + l15) * DH + ks * 32 + quad * 8];

            auto stageK = [&](int buf, int kt) {
                for (int i = 0; i < 2; i++) {
                    int f = w * 2 + i;
                    int ks = f >> 3, ni = f & 7;
                    gld16(&Ks[buf][f * 512],
                          kbase + (size_t)(kt * 128 + ni * 16 + l15) * DH + ks * 32 + quad * 8);
                }
            };
            auto stageV = [&](int kt) {
                const bf16* vt = vfrag + (size_t)kt * 8192;
                for (int i = 0; i < 2; i++) {
                    int f = w * 2 + i;
                    gld16(&Vs[f * 512], vt + f * 512 + lane * 8);
                }
            };

            const bf16 one = (bf16)1.0f;
            const bf16x8 ones = {one, one, one, one, one, one, one, one};
            const f32x4 z4 = {0.f, 0.f, 0.f, 0.f};
            f32x4 acco[4], accd;
            for (int no = 0; no < 4; no++) acco[no] = z4;
            accd = z4;

            stageK(0, 0);

            for (int kt = 0; kt <= qt; kt++) {
                int buf = kt & 1;
                asm volatile("s_waitcnt vmcnt(0)\n\ts_barrier" ::: "memory");
                __builtin_amdgcn_sched_barrier(0);
                stageV(kt);
                if (kt < qt) stageK(buf ^ 1, kt + 1);
                const bf16* Kbuf = Ks[buf];

                f32x4 accs[8];
                for (int ni = 0; ni < 8; ni++) accs[ni] = z4;
                __builtin_amdgcn_s_setprio(1);
                for (int ks = 0; ks < 2; ks++)
                    for (int ni = 0; ni < 8; ni++) {
                        bf16x8 ak = *(const bf16x8*)&Kbuf[(ks * 8 + ni) * 512 + lane * 8];
                        accs[ni] = MFMA16(ak, aq[ks], accs[ni]);
                    }
                __builtin_amdgcn_s_setprio(0);

                if (kt == qt) {
                    int ql = w * 16 + l15;
                    for (int ni = 0; ni < 8; ni++) {
                        int kvl = ni * 16 + quad * 4;
                        for (int r = 0; r < 4; r++)
                            if (kvl + r > ql) accs[ni][r] = -1e30f;
                    }
                }

                bf16x4 pt[8];
                for (int ni = 0; ni < 8; ni++)
                    for (int r = 0; r < 4; r++)
                        pt[ni][r] = (bf16)EXP2(accs[ni][r]);

                if (kt < qt) {
                    asm volatile("s_waitcnt vmcnt(2)\n\ts_barrier" ::: "memory");
                } else {
                    asm volatile("s_waitcnt vmcnt(0)\n\ts_barrier" ::: "memory");
                }
                __builtin_amdgcn_sched_barrier(0);

                __builtin_amdgcn_s_setprio(1);
                for (int p4 = 0; p4 < 4; p4++) {
                    bf16x8 ap;
                    for (int j = 0; j < 4; j++) {
                        ap[j] = pt[2 * p4][j];
                        ap[4 + j] = pt[2 * p4 + 1][j];
                    }
                    accd = MFMA16(ap, ones, accd);
                    for (int no = 0; no < 4; no++) {
                        bf16x8 bv = *(const bf16x8*)&Vs[(p4 * 4 + no) * 512 + lane * 8];
                        acco[no] = MFMA16(ap, bv, acco[no]);
                    }
                }
                __builtin_amdgcn_s_setprio(0);
            }

            for (int r = 0; r < 4; r++) {
                float inv = 1.0f / accd[r];
                int q = qr0 + quad * 4 + r;
                size_t rowbase = ((size_t)b * SEQ + q) * DM + h * DH;
                for (int no = 0; no < 4; no++)
                    Zb[rowbase + no * 16 + l15] = (bf16)(acco[no][r] * inv);
            }
        }
    }
    gridbar(bcnt, bgen, 256);

    // ======================= P3: out (8-wave 128^2 tile) ===================
    {
        int mt = bid & 31, nt = bid >> 5;     // 32 x 8 = 256 tiles
        int wr = w >> 2, wc = w & 3;          // 2M x 4N; per-wave 64x32
        int m0 = mt * 128, n0 = nt * 128;

        // slot = 16 KB (A 8KB rows 0..127 | B 8KB rows 0..127); ring 4 = 64KB
        int P0 = t * 16;                      // covers full 8 KB region
        int L0 = P0 ^ (((P0 >> 7) & 3) << 4);
        int row0 = L0 >> 6, kc0 = (L0 >> 4) & 3;
        const bf16* gA0 = Zb + (size_t)(m0 + row0) * DM + kc0 * 8;
        const bf16* gB0 = woT + (size_t)(n0 + row0) * DM + kc0 * 8;

        auto stage = [&](int ts) {            // 2 loads per wave per step
            char* sb = sm + (ts & 3) * 16384;
            int ko = ts * 32;
            gld16(sb + w * 1024, gA0 + ko);
            gld16(sb + 8192 + w * 1024, gB0 + ko);
        };

        int aoff[4], boff[2];
#pragma unroll
        for (int mi = 0; mi < 4; mi++) {
            int row = wr * 64 + mi * 16 + l15;
            aoff[mi] = row * 64 + ((quad ^ ((row >> 1) & 3)) << 4);
        }
#pragma unroll
        for (int ni = 0; ni < 2; ni++) {
            int row = wc * 32 + ni * 16 + l15;
            boff[ni] = 8192 + row * 64 + ((quad ^ ((row >> 1) & 3)) << 4);
        }

        const f32x4 z4 = {0.f, 0.f, 0.f, 0.f};
        f32x4 acc[4][2];
#pragma unroll
        for (int mi = 0; mi < 4; mi++)
#pragma unroll
            for (int ni = 0; ni < 2; ni++) acc[mi][ni] = z4;

        auto kstep = [&](int tt, bool st) {
            const char* sb = sm + (tt & 3) * 16384;
            bf16x8 bfr[2], afr[4];
#pragma unroll
            for (int ni = 0; ni < 2; ni++) bfr[ni] = *(const bf16x8*)(sb + boff[ni]);
#pragma unroll
            for (int mi = 0; mi < 4; mi++) afr[mi] = *(const bf16x8*)(sb + aoff[mi]);
            if (st) stage(tt + 3);
            __builtin_amdgcn_s_setprio(1);
#pragma unroll
            for (int mi = 0; mi < 4; mi++)
#pragma unroll
                for (int ni = 0; ni < 2; ni++)
                    acc[mi][ni] = MFMA16(afr[mi], bfr[ni], acc[mi][ni]);
            __builtin_amdgcn_s_setprio(0);
        };

        stage(0); stage(1); stage(2);   // 6 loads/wave in flight

#pragma unroll 1
        for (int tt = 0; tt < 29; tt++) {
            // step tt's 2 loads older than the newest 4 (steps tt+1, tt+2)
            asm volatile("s_waitcnt vmcnt(4)\n\ts_barrier" ::: "memory");
            __builtin_amdgcn_sched_barrier(0);
            kstep(tt, true);
        }
        asm volatile("s_waitcnt vmcnt(4)\n\ts_barrier" ::: "memory");
        __builtin_amdgcn_sched_barrier(0);
        kstep(29, false);
        asm volatile("s_waitcnt vmcnt(2)\n\ts_barrier" ::: "memory");
        __builtin_amdgcn_sched_barrier(0);
        kstep(30, false);
        asm volatile("s_waitcnt vmcnt(0)\n\ts_barrier" ::: "memory");
        __builtin_amdgcn_sched_barrier(0);
        kstep(31, false);

        // epilogue: s = m0 + wr*64 + mi*16 + quad*4 + r,
        //           d = n0 + wc*32 + ni*16 + l15
#pragma unroll
        for (int ni = 0; ni < 2; ni++) {
            int d = n0 + wc * 32 + ni * 16 + l15;
            float bia = bO[d];
#pragma unroll
            for (int mi = 0; mi < 4; mi++)
#pragma unroll
                for (int r = 0; r < 4; r++) {
                    int s = m0 + wr * 64 + mi * 16 + quad * 4 + r;
                    out[(size_t)s * DM + d] = acc[mi][ni][r] + bia;
                }
        }
    }
}

// ---------------------------------------------------------------------------
extern "C" void kernel_launch(void* const* d_in, const int* in_sizes, int n_in,
                              void* d_out, int out_size, void* d_ws, size_t ws_size,
                              hipStream_t stream) {
    const float* x  = (const float*)d_in[0];
    const float* WQ = (const float*)d_in[1];
    const float* WK = (const float*)d_in[2];
    const float* WV = (const float*)d_in[3];
    const float* WO = (const float*)d_in[4];
    const float* bQ = (const float*)d_in[5];
    const float* bK = (const float*)d_in[6];
    const float* bV = (const float*)d_in[7];
    const float* bO = (const float*)d_in[8];
    float* out = (float*)d_out;

    char* w = (char*)d_ws;
    bf16* xb    = (bf16*)(w + 0);                      //  8 MB [4096][1024]
    bf16* wqkvT = (bf16*)(w + (8u << 20));             //  6 MB [p][he][k]
    bf16* woT   = (bf16*)(w + (14u << 20));            //  2 MB [d][he]
    bf16* Qb    = (bf16*)(w + (16u << 20));            //  8 MB [b][h][s][e]
    bf16* Kb    = (bf16*)(w + (24u << 20));            //  8 MB [b][h][s][e]
    bf16* VTf   = (bf16*)(w + (32u << 20));            //  8 MB [bh][kt][16][512]
    bf16* Zb    = (bf16*)(w + (40u << 20));            //  8 MB [b][s][h*64+e]
    int*  bar   = (int*)(w + (48u << 20));             //  barrier state

    hipMemsetAsync(bar, 0, 64, stream);
    k_mega<<<256, 512, 0, stream>>>(x, WQ, WK, WV, WO, bQ, bK, bV, bO, out,
                                    xb, wqkvT, woT, Qb, Kb, VTf, Zb, bar);
}

// Round 9
// 165.945 us; speedup vs baseline: 1.4678x; 1.4678x over previous
//
#include <hip/hip_runtime.h>

#define SEQ 2048
#define BATCH 2
#define DM 1024
#define NH 16
#define DH 64

typedef __bf16 bf16;
typedef __bf16 bf16x8 __attribute__((ext_vector_type(8)));
typedef __bf16 bf16x4 __attribute__((ext_vector_type(4)));
typedef float f32x4 __attribute__((ext_vector_type(4)));

#define MFMA16(a, b, c) __builtin_amdgcn_mfma_f32_16x16x32_bf16((a), (b), (c), 0, 0, 0)

#if __has_builtin(__builtin_amdgcn_exp2f)
#define EXP2(x) __builtin_amdgcn_exp2f(x)
#else
#define EXP2(x) exp2f(x)
#endif

// Q scale folds 1/sqrt(64) and log2(e) so softmax uses bare v_exp_f32 (exp2)
#define QSCALE 0.18033688f

// async global->LDS, 16B per lane; LDS dest = wave-uniform base + lane*16
typedef __attribute__((address_space(3))) void lds_void;
typedef __attribute__((address_space(1))) void glb_void;
__device__ __forceinline__ void gld16(void* lds, const void* g) {
    __builtin_amdgcn_global_load_lds((const glb_void*)g, (lds_void*)lds, 16, 0, 0);
}

// ---------------------------------------------------------------------------
// K0: fused prep. blocks [0,2048): cast x -> bf16. [2048,2816): transpose
// W_{Q,K,V} -> wT [p][he][k]. [2816,3072): transpose W_O -> woT [d][he].
// (Streaming, no inter-block reuse -> T1 XCD swizzle is null here; unchanged.)
// ---------------------------------------------------------------------------
__global__ __launch_bounds__(256) void k_prep(const float* __restrict__ x,
                                              const float* __restrict__ WQ,
                                              const float* __restrict__ WK,
                                              const float* __restrict__ WV,
                                              const float* __restrict__ WO,
                                              bf16* __restrict__ xb,
                                              bf16* __restrict__ wT,
                                              bf16* __restrict__ woT) {
    int bx = blockIdx.x;
    int t = threadIdx.x;
    if (bx < 2048) {
        int g = bx * 256 + t;
        const float4* x4 = (const float4*)x;
        float4 a = x4[2 * g];
        float4 b = x4[2 * g + 1];
        bf16x8 o;
        o[0] = (bf16)a.x; o[1] = (bf16)a.y; o[2] = (bf16)a.z; o[3] = (bf16)a.w;
        o[4] = (bf16)b.x; o[5] = (bf16)b.y; o[6] = (bf16)b.z; o[7] = (bf16)b.w;
        *(bf16x8*)(xb + 8 * g) = o;
        return;
    }
    __shared__ bf16 T[64 * 65];
    if (bx < 2816) {
        int id = bx - 2048;
        int kt = id & 15, ph = id >> 4;
        int p = ph >> 4, h = ph & 15;
        const float* Wp = (p == 0) ? WQ : (p == 1) ? WK : WV;
        const float* src = Wp + ((size_t)h * DM + (size_t)kt * 64) * DH;
        for (int i = 0; i < 4; i++) {
            int c = t + 256 * i;
            int r = c >> 4;
            int col = (c & 15) * 4;
            float4 v = *(const float4*)&src[r * 64 + col];
            T[(col + 0) * 65 + r] = (bf16)v.x;
            T[(col + 1) * 65 + r] = (bf16)v.y;
            T[(col + 2) * 65 + r] = (bf16)v.z;
            T[(col + 3) * 65 + r] = (bf16)v.w;
        }
        __syncthreads();
        bf16* dst = wT + (size_t)ph * 64 * DM + (size_t)kt * 64;
        for (int i = 0; i < 2; i++) {
            int c = t + 256 * i;
            int e = c >> 3;
            int k0 = (c & 7) * 8;
            bf16x8 o;
            for (int j = 0; j < 8; j++) o[j] = T[e * 65 + k0 + j];
            *(bf16x8*)&dst[(size_t)e * DM + k0] = o;
        }
    } else {
        int id = bx - 2816;
        int ht = id & 15, dt = id >> 4;
        for (int i = 0; i < 4; i++) {
            int c = t + 256 * i;
            int r = c >> 4;
            int col = (c & 15) * 4;
            float4 v = *(const float4*)&WO[((size_t)(ht * 64 + r)) * DM + dt * 64 + col];
            T[(col + 0) * 65 + r] = (bf16)v.x;
            T[(col + 1) * 65 + r] = (bf16)v.y;
            T[(col + 2) * 65 + r] = (bf16)v.z;
            T[(col + 3) * 65 + r] = (bf16)v.w;
        }
        __syncthreads();
        for (int i = 0; i < 2; i++) {
            int c = t + 256 * i;
            int d = c >> 3;
            int h0 = (c & 7) * 8;
            bf16x8 o;
            for (int j = 0; j < 8; j++) o[j] = T[d * 65 + h0 + j];
            *(bf16x8*)&woT[((size_t)(dt * 64 + d)) * DM + ht * 64 + h0] = o;
        }
    }
}

// ---------------------------------------------------------------------------
// K1: QKV projection, 256x256 tile deep-pipeline (R7 body). R9 delta: T1
// XCD-chunked block swizzle. Old grid (16,4,3) gave xcd = mt%8, scattering
// each B-panel (nt,p; 512 KB, shared by 16 mt-blocks) across all 8 XCD L2s
// (8x replication). New 1D grid 192 with bijective v = (bid%8)*24 + bid/8
// (192 = 8x24 exact, ERRATA#11-safe): each XCD owns 24 consecutive v =
// <=2 B-panels -> replication 8x -> <=2x. Pure index remap, no numeric change.
// ---------------------------------------------------------------------------
__global__ __launch_bounds__(512, 2) void k_qkv(const bf16* __restrict__ xb,
                                                const bf16* __restrict__ wT,
                                                const float* __restrict__ bQ,
                                                const float* __restrict__ bK,
                                                const float* __restrict__ bV,
                                                bf16* __restrict__ Qb,
                                                bf16* __restrict__ Kb,
                                                bf16* __restrict__ VTf) {
    int bid = blockIdx.x;
    int v = (bid & 7) * 24 + (bid >> 3);   // bijective over [0,192)
    int mt = v & 15;
    int pid = v >> 4;                      // panel id = nt + 4*p, [0,12)
    int nt = pid & 3, p = pid >> 2;
    __shared__ __align__(16) char sm[131072];   // 4 slots x (A 16KB | B 16KB)
    int t = threadIdx.x;
    int lane = t & 63, w = t >> 6;
    int l15 = lane & 15, quad = lane >> 4;
    int wr = w >> 2, wc = w & 3;               // 2M x 4N wave grid
    int m0 = mt * 256, n0 = nt * 256;

    // ---- pre-swizzled global sources for staging (phys P -> logical L) ----
    int P0 = t * 16;
    int L0 = P0 ^ (((P0 >> 7) & 3) << 4);
    int row0 = L0 >> 6, kc0 = (L0 >> 4) & 3;
    int P1 = 8192 + t * 16;
    int L1 = P1 ^ (((P1 >> 7) & 3) << 4);
    int row1 = L1 >> 6, kc1 = (L1 >> 4) & 3;
    const bf16* gA0 = xb + (size_t)(m0 + row0) * DM + kc0 * 8;
    const bf16* gA1 = xb + (size_t)(m0 + row1) * DM + kc1 * 8;
    const bf16* gB0 = wT + (size_t)(p * 1024 + n0 + row0) * DM + kc0 * 8;
    const bf16* gB1 = wT + (size_t)(p * 1024 + n0 + row1) * DM + kc1 * 8;

    auto stage = [&](int ts, bool bsel) {
        char* sb = sm + (ts & 3) * 32768;
        int ko = ts * 32;   // 32 k-elements per step
        if (!bsel) {
            gld16(sb + w * 1024, gA0 + ko);
            gld16(sb + 8192 + w * 1024, gA1 + ko);
        } else {
            gld16(sb + 16384 + w * 1024, gB0 + ko);
            gld16(sb + 16384 + 8192 + w * 1024, gB1 + ko);
        }
    };

    // ---- swizzled ds_read offsets (slot-relative, constant per thread) ----
    int aoff[8], boff[4];
#pragma unroll
    for (int mi = 0; mi < 8; mi++) {
        int row = wr * 128 + mi * 16 + l15;
        aoff[mi] = row * 64 + ((quad ^ ((row >> 1) & 3)) << 4);
    }
#pragma unroll
    for (int ni = 0; ni < 4; ni++) {
        int row = wc * 64 + ni * 16 + l15;
        boff[ni] = 16384 + row * 64 + ((quad ^ ((row >> 1) & 3)) << 4);
    }

    const f32x4 z4 = {0.f, 0.f, 0.f, 0.f};
    f32x4 acc[8][4];
#pragma unroll
    for (int mi = 0; mi < 8; mi++)
#pragma unroll
        for (int ni = 0; ni < 4; ni++) acc[mi][ni] = z4;

    auto kstep = [&](int tt, bool st) {
        const char* sb = sm + (tt & 3) * 32768;
        bf16x8 bfr[4], afr[4];
#pragma unroll
        for (int ni = 0; ni < 4; ni++) bfr[ni] = *(const bf16x8*)(sb + boff[ni]);
#pragma unroll
        for (int mi = 0; mi < 4; mi++) afr[mi] = *(const bf16x8*)(sb + aoff[mi]);
        if (st) stage(tt + 3, false);
        __builtin_amdgcn_s_setprio(1);
#pragma unroll
        for (int mi = 0; mi < 4; mi++)
#pragma unroll
            for (int ni = 0; ni < 4; ni++)
                acc[mi][ni] = MFMA16(afr[mi], bfr[ni], acc[mi][ni]);
        __builtin_amdgcn_s_setprio(0);
        bf16x8 afr2[4];
#pragma unroll
        for (int mi = 0; mi < 4; mi++) afr2[mi] = *(const bf16x8*)(sb + aoff[4 + mi]);
        if (st) stage(tt + 3, true);
        __builtin_amdgcn_s_setprio(1);
#pragma unroll
        for (int mi = 0; mi < 4; mi++)
#pragma unroll
            for (int ni = 0; ni < 4; ni++)
                acc[4 + mi][ni] = MFMA16(afr2[mi], bfr[ni], acc[4 + mi][ni]);
        __builtin_amdgcn_s_setprio(0);
    };

    // prologue: stage steps 0,1,2 (12 loads; FIFO order step-major)
    stage(0, false); stage(0, true);
    stage(1, false); stage(1, true);
    stage(2, false); stage(2, true);

#pragma unroll 1
    for (int tt = 0; tt < 29; tt++) {
        // step tt's 4 loads are older than the newest 8 (steps tt+1,tt+2)
        asm volatile("s_waitcnt vmcnt(8)\n\ts_barrier" ::: "memory");
        __builtin_amdgcn_sched_barrier(0);
        kstep(tt, true);
    }
    asm volatile("s_waitcnt vmcnt(8)\n\ts_barrier" ::: "memory");
    __builtin_amdgcn_sched_barrier(0);
    kstep(29, false);
    asm volatile("s_waitcnt vmcnt(4)\n\ts_barrier" ::: "memory");
    __builtin_amdgcn_sched_barrier(0);
    kstep(30, false);
    asm volatile("s_waitcnt vmcnt(0)\n\ts_barrier" ::: "memory");
    __builtin_amdgcn_sched_barrier(0);
    kstep(31, false);

    // ---- epilogue: C row = m0 + wr*128 + mi*16 + quad*4 + r,
    //                C col = n0 + wc*64 + ni*16 + l15 ----
    int b = m0 >> 11;   // uniform (256 | 2048)
    if (p < 2) {
        const float* bias = (p == 0) ? bQ : bK;
        bf16* dst = (p == 0) ? Qb : Kb;
        float scale = (p == 0) ? QSCALE : 1.0f;
#pragma unroll
        for (int ni = 0; ni < 4; ni++) {
            int he = n0 + wc * 64 + ni * 16 + l15;
            int h = he >> 6, e = he & 63;
            float bia = bias[he];
            size_t rb = (size_t)(b * NH + h) * SEQ * DH + e;
#pragma unroll
            for (int mi = 0; mi < 8; mi++)
#pragma unroll
                for (int r = 0; r < 4; r++) {
                    int s = ((m0 + wr * 128 + mi * 16 + quad * 4 + r) & 2047);
                    dst[rb + (size_t)s * DH] = (bf16)((acc[mi][ni][r] + bia) * scale);
                }
        }
    } else {
        // paired-fragment V store (contract with k_attn preserved):
        // kv_local = (mi>>1)*32 + (mi&1)*16 + quad*4 + r; no = ni
        // f = (mi>>1)*4 + ni; slot (quad<<4)|l15; elem j = (mi&1)*4 + r
#pragma unroll
        for (int ni = 0; ni < 4; ni++) {
            int he = n0 + wc * 64 + ni * 16 + l15;
            int h = he >> 6;
            float bia = bV[he];
#pragma unroll
            for (int mi = 0; mi < 8; mi++) {
                int kvl = (mt & 7) * 256 + wr * 128 + mi * 16;
                int kt = kvl >> 7;
                int f = (mi >> 1) * 4 + ni;
                size_t base = (((size_t)(b * NH + h) * 16 + kt) * 16 + f) * 512
                              + (size_t)((quad << 4) | l15) * 8 + (mi & 1) * 4;
                bf16x4 o;
#pragma unroll
                for (int r = 0; r < 4; r++) o[r] = (bf16)(acc[mi][ni][r] + bia);
                *(bf16x4*)&VTf[base] = o;
            }
        }
    }
}

// ---------------------------------------------------------------------------
// K2: flash attention (R7 body, unchanged). Grid (32,16) already has ideal
// XCD locality: xcd = (bh + 32y)%8 = bh%8 -> all 16 blocks sharing one bh's
// K/V land on one XCD, and CU block-pairs (c, c+256) give qt sums of 17.
// K dbuf (32 KB) + single V buf (16 KB) = 48 KB -> 3 blocks/CU. Split
// counted-vmcnt waits; setprio around QK and PV MFMA clusters.
// ---------------------------------------------------------------------------
__global__ __launch_bounds__(512, 4) void k_attn(const bf16* __restrict__ Qb,
                                                 const bf16* __restrict__ Kb,
                                                 const bf16* __restrict__ VTf,
                                                 bf16* __restrict__ Zb) {
    int bh = blockIdx.x;
    int y = blockIdx.y;
    int qt = (y < 8) ? y : 23 - y;
    int h = bh & 15, b = bh >> 4;
    __shared__ __align__(16) bf16 Ks[2][16 * 512];   // 32 KB
    __shared__ __align__(16) bf16 Vs[16 * 512];      // 16 KB
    int t = threadIdx.x;
    int lane = t & 63, w = t >> 6;
    int l15 = lane & 15, quad = lane >> 4;

    const bf16* qbase = Qb + (size_t)bh * SEQ * DH;
    const bf16* kbase = Kb + (size_t)bh * SEQ * DH;
    const bf16* vfrag = VTf + (size_t)bh * 16 * 8192;

    int qr0 = qt * 128 + w * 16;
    bf16x8 aq[2];   // Q as B-operand: lane holds q=qr0+l15, e=ks*32+quad*8+j
    for (int ks = 0; ks < 2; ks++)
        aq[ks] = *(const bf16x8*)&qbase[(size_t)(qr0 + l15) * DH + ks * 32 + quad * 8];

    auto stageK = [&](int buf, int kt) {
        for (int i = 0; i < 2; i++) {
            int f = w * 2 + i;
            int ks = f >> 3, ni = f & 7;
            gld16(&Ks[buf][f * 512],
                  kbase + (size_t)(kt * 128 + ni * 16 + l15) * DH + ks * 32 + quad * 8);
        }
    };
    auto stageV = [&](int kt) {
        const bf16* vt = vfrag + (size_t)kt * 8192;
        for (int i = 0; i < 2; i++) {
            int f = w * 2 + i;
            gld16(&Vs[f * 512], vt + f * 512 + lane * 8);
        }
    };

    const bf16 one = (bf16)1.0f;
    const bf16x8 ones = {one, one, one, one, one, one, one, one};
    const f32x4 z4 = {0.f, 0.f, 0.f, 0.f};
    f32x4 acco[4], accd;
    for (int no = 0; no < 4; no++) acco[no] = z4;
    accd = z4;

    stageK(0, 0);

    for (int kt = 0; kt <= qt; kt++) {
        int buf = kt & 1;
        // K[kt] ready (only K outstanding; cover = prev QK+softmax+PV)
        asm volatile("s_waitcnt vmcnt(0)\n\ts_barrier" ::: "memory");
        __builtin_amdgcn_sched_barrier(0);
        stageV(kt);        // V[kt] lands during QK+softmax below
        if (kt < qt) stageK(buf ^ 1, kt + 1);
        const bf16* Kbuf = Ks[buf];

        // S^T = K x Q^T : lane holds q=l15, kv=ni*16+quad*4+r
        f32x4 accs[8];
        for (int ni = 0; ni < 8; ni++) accs[ni] = z4;
        __builtin_amdgcn_s_setprio(1);
        for (int ks = 0; ks < 2; ks++)
            for (int ni = 0; ni < 8; ni++) {
                bf16x8 ak = *(const bf16x8*)&Kbuf[(ks * 8 + ni) * 512 + lane * 8];
                accs[ni] = MFMA16(ak, aq[ks], accs[ni]);
            }
        __builtin_amdgcn_s_setprio(0);

        if (kt == qt) {   // causal mask on diagonal tile
            int ql = w * 16 + l15;
            for (int ni = 0; ni < 8; ni++) {
                int kvl = ni * 16 + quad * 4;
                for (int r = 0; r < 4; r++)
                    if (kvl + r > ql) accs[ni][r] = -1e30f;
            }
        }

        // P^T = exp2(S^T) in registers
        bf16x4 pt[8];
        for (int ni = 0; ni < 8; ni++)
            for (int r = 0; r < 4; r++)
                pt[ni][r] = (bf16)EXP2(accs[ni][r]);

        // V[kt] done (FIFO [V,V,K,K]); K[kt+1] may stay in flight through PV
        if (kt < qt) {
            asm volatile("s_waitcnt vmcnt(2)\n\ts_barrier" ::: "memory");
        } else {
            asm volatile("s_waitcnt vmcnt(0)\n\ts_barrier" ::: "memory");
        }
        __builtin_amdgcn_sched_barrier(0);

        // O += P(A) x V(B); V frags linear b128. ones-B -> per-lane denominator.
        __builtin_amdgcn_s_setprio(1);
        for (int p4 = 0; p4 < 4; p4++) {
            bf16x8 ap;
            for (int j = 0; j < 4; j++) {
                ap[j] = pt[2 * p4][j];
                ap[4 + j] = pt[2 * p4 + 1][j];
            }
            accd = MFMA16(ap, ones, accd);
            for (int no = 0; no < 4; no++) {
                bf16x8 bv = *(const bf16x8*)&Vs[(p4 * 4 + no) * 512 + lane * 8];
                acco[no] = MFMA16(ap, bv, acco[no]);
            }
        }
        __builtin_amdgcn_s_setprio(0);
    }

    // epilogue: O[q][e], per-lane denominator; 32B runs along e
    for (int r = 0; r < 4; r++) {
        float inv = 1.0f / accd[r];
        int q = qr0 + quad * 4 + r;
        size_t rowbase = ((size_t)b * SEQ + q) * DM + h * DH;
        for (int no = 0; no < 4; no++)
            Zb[rowbase + no * 16 + l15] = (bf16)(acco[no][r] * inv);
    }
}

// ---------------------------------------------------------------------------
// K3: out[s][d] = Zb @ woT + bO, 128x128 tile deep-pipeline (R7 body). R9
// delta: T1 XCD swizzle. Old grid (32,8) gave xcd = mt%8 -> each woT panel
// (nt; 256 KB, shared by 32 mt-blocks) replicated in all 8 XCD L2s. New 1D
// grid 256, v = (bid%8)*32 + bid/8 (bijective, 256 = 8x32): each XCD owns
// exactly one nt-panel -> replication 8x -> 1x.
// ---------------------------------------------------------------------------
__global__ __launch_bounds__(256, 2) void k_out(const bf16* __restrict__ Zb,
                                                const bf16* __restrict__ woT,
                                                const float* __restrict__ bO,
                                                float* __restrict__ out) {
    int bid = blockIdx.x;
    int v = (bid & 7) * 32 + (bid >> 3);   // bijective over [0,256)
    int mt = v & 31, nt = v >> 5;
    __shared__ __align__(16) char sm[65536];   // 4 slots x (A 8KB | B 8KB)
    int t = threadIdx.x;
    int lane = t & 63, w = t >> 6;
    int l15 = lane & 15, quad = lane >> 4;
    int wr = w >> 1, wc = w & 1;               // 2M x 2N wave grid
    int m0 = mt * 128, n0 = nt * 128;

    // pre-swizzled global sources (phys P -> logical L), regions of 8KB
    int P0 = t * 16;
    int L0 = P0 ^ (((P0 >> 7) & 3) << 4);
    int row0 = L0 >> 6, kc0 = (L0 >> 4) & 3;
    int P1 = 4096 + t * 16;
    int L1 = P1 ^ (((P1 >> 7) & 3) << 4);
    int row1 = L1 >> 6, kc1 = (L1 >> 4) & 3;
    const bf16* gA0 = Zb + (size_t)(m0 + row0) * DM + kc0 * 8;
    const bf16* gA1 = Zb + (size_t)(m0 + row1) * DM + kc1 * 8;
    const bf16* gB0 = woT + (size_t)(n0 + row0) * DM + kc0 * 8;
    const bf16* gB1 = woT + (size_t)(n0 + row1) * DM + kc1 * 8;

    auto stage = [&](int ts) {
        char* sb = sm + (ts & 3) * 16384;
        int ko = ts * 32;
        gld16(sb + w * 1024, gA0 + ko);
        gld16(sb + 4096 + w * 1024, gA1 + ko);
        gld16(sb + 8192 + w * 1024, gB0 + ko);
        gld16(sb + 8192 + 4096 + w * 1024, gB1 + ko);
    };

    int aoff[4], boff[4];
#pragma unroll
    for (int mi = 0; mi < 4; mi++) {
        int row = wr * 64 + mi * 16 + l15;
        aoff[mi] = row * 64 + ((quad ^ ((row >> 1) & 3)) << 4);
    }
#pragma unroll
    for (int ni = 0; ni < 4; ni++) {
        int row = wc * 64 + ni * 16 + l15;
        boff[ni] = 8192 + row * 64 + ((quad ^ ((row >> 1) & 3)) << 4);
    }

    const f32x4 z4 = {0.f, 0.f, 0.f, 0.f};
    f32x4 acc[4][4];
#pragma unroll
    for (int mi = 0; mi < 4; mi++)
#pragma unroll
        for (int ni = 0; ni < 4; ni++) acc[mi][ni] = z4;

    auto kstep = [&](int tt, bool st) {
        const char* sb = sm + (tt & 3) * 16384;
        bf16x8 bfr[4], afr[4];
#pragma unroll
        for (int ni = 0; ni < 4; ni++) bfr[ni] = *(const bf16x8*)(sb + boff[ni]);
#pragma unroll
        for (int mi = 0; mi < 4; mi++) afr[mi] = *(const bf16x8*)(sb + aoff[mi]);
        if (st) stage(tt + 3);
        __builtin_amdgcn_s_setprio(1);
#pragma unroll
        for (int mi = 0; mi < 4; mi++)
#pragma unroll
            for (int ni = 0; ni < 4; ni++)
                acc[mi][ni] = MFMA16(afr[mi], bfr[ni], acc[mi][ni]);
        __builtin_amdgcn_s_setprio(0);
    };

    stage(0); stage(1); stage(2);   // 12 loads in flight

#pragma unroll 1
    for (int tt = 0; tt < 29; tt++) {
        // step tt's 4 loads are older than the newest 8 (steps tt+1,tt+2)
        asm volatile("s_waitcnt vmcnt(8)\n\ts_barrier" ::: "memory");
        __builtin_amdgcn_sched_barrier(0);
        kstep(tt, true);
    }
    asm volatile("s_waitcnt vmcnt(8)\n\ts_barrier" ::: "memory");
    __builtin_amdgcn_sched_barrier(0);
    kstep(29, false);
    asm volatile("s_waitcnt vmcnt(4)\n\ts_barrier" ::: "memory");
    __builtin_amdgcn_sched_barrier(0);
    kstep(30, false);
    asm volatile("s_waitcnt vmcnt(0)\n\ts_barrier" ::: "memory");
    __builtin_amdgcn_sched_barrier(0);
    kstep(31, false);

    // epilogue: s = m0 + wr*64 + mi*16 + quad*4 + r, d = n0 + wc*64 + ni*16 + l15
#pragma unroll
    for (int ni = 0; ni < 4; ni++) {
        int d = n0 + wc * 64 + ni * 16 + l15;
        float bia = bO[d];
#pragma unroll
        for (int mi = 0; mi < 4; mi++)
#pragma unroll
            for (int r = 0; r < 4; r++) {
                int s = m0 + wr * 64 + mi * 16 + quad * 4 + r;
                out[(size_t)s * DM + d] = acc[mi][ni][r] + bia;
            }
    }
}

// ---------------------------------------------------------------------------
extern "C" void kernel_launch(void* const* d_in, const int* in_sizes, int n_in,
                              void* d_out, int out_size, void* d_ws, size_t ws_size,
                              hipStream_t stream) {
    const float* x  = (const float*)d_in[0];
    const float* WQ = (const float*)d_in[1];
    const float* WK = (const float*)d_in[2];
    const float* WV = (const float*)d_in[3];
    const float* WO = (const float*)d_in[4];
    const float* bQ = (const float*)d_in[5];
    const float* bK = (const float*)d_in[6];
    const float* bV = (const float*)d_in[7];
    const float* bO = (const float*)d_in[8];
    float* out = (float*)d_out;

    char* w = (char*)d_ws;
    bf16* xb    = (bf16*)(w + 0);                      //  8 MB [4096][1024]
    bf16* wqkvT = (bf16*)(w + (8u << 20));             //  6 MB [p][he][k]
    bf16* woT   = (bf16*)(w + (14u << 20));            //  2 MB [d][he]
    bf16* Qb    = (bf16*)(w + (16u << 20));            //  8 MB [b][h][s][e]
    bf16* Kb    = (bf16*)(w + (24u << 20));            //  8 MB [b][h][s][e]
    bf16* VTf   = (bf16*)(w + (32u << 20));            //  8 MB [bh][kt][16][512]
    bf16* Zb    = (bf16*)(w + (40u << 20));            //  8 MB [b][s][h*64+e]

    k_prep<<<3072, 256, 0, stream>>>(x, WQ, WK, WV, WO, xb, wqkvT, woT);
    k_qkv<<<192, 512, 0, stream>>>(xb, wqkvT, bQ, bK, bV, Qb, Kb, VTf);
    k_attn<<<dim3(32, 16), 512, 0, stream>>>(Qb, Kb, VTf, Zb);
    k_out<<<256, 256, 0, stream>>>(Zb, woT, bO, out);
}

// Round 10
// 157.479 us; speedup vs baseline: 1.5467x; 1.0538x over previous
//
#include <hip/hip_runtime.h>

#define SEQ 2048
#define BATCH 2
#define DM 1024
#define NH 16
#define DH 64

typedef __bf16 bf16;
typedef __bf16 bf16x8 __attribute__((ext_vector_type(8)));
typedef __bf16 bf16x4 __attribute__((ext_vector_type(4)));
typedef float f32x4 __attribute__((ext_vector_type(4)));

#define MFMA16(a, b, c) __builtin_amdgcn_mfma_f32_16x16x32_bf16((a), (b), (c), 0, 0, 0)

#if __has_builtin(__builtin_amdgcn_exp2f)
#define EXP2(x) __builtin_amdgcn_exp2f(x)
#else
#define EXP2(x) exp2f(x)
#endif

// Q scale folds 1/sqrt(64) and log2(e) so softmax uses bare v_exp_f32 (exp2)
#define QSCALE 0.18033688f

// async global->LDS, 16B per lane; LDS dest = wave-uniform base + lane*16
typedef __attribute__((address_space(3))) void lds_void;
typedef __attribute__((address_space(1))) void glb_void;
__device__ __forceinline__ void gld16(void* lds, const void* g) {
    __builtin_amdgcn_global_load_lds((const glb_void*)g, (lds_void*)lds, 16, 0, 0);
}

// ---------------------------------------------------------------------------
// K0: fused prep. blocks [0,2048): cast x -> bf16. [2048,2816): transpose
// W_{Q,K,V} -> wT [p][he][k] (== flat [3072][1024]). [2816,3072): W_O -> woT.
// ---------------------------------------------------------------------------
__global__ __launch_bounds__(256) void k_prep(const float* __restrict__ x,
                                              const float* __restrict__ WQ,
                                              const float* __restrict__ WK,
                                              const float* __restrict__ WV,
                                              const float* __restrict__ WO,
                                              bf16* __restrict__ xb,
                                              bf16* __restrict__ wT,
                                              bf16* __restrict__ woT) {
    int bx = blockIdx.x;
    int t = threadIdx.x;
    if (bx < 2048) {
        int g = bx * 256 + t;
        const float4* x4 = (const float4*)x;
        float4 a = x4[2 * g];
        float4 b = x4[2 * g + 1];
        bf16x8 o;
        o[0] = (bf16)a.x; o[1] = (bf16)a.y; o[2] = (bf16)a.z; o[3] = (bf16)a.w;
        o[4] = (bf16)b.x; o[5] = (bf16)b.y; o[6] = (bf16)b.z; o[7] = (bf16)b.w;
        *(bf16x8*)(xb + 8 * g) = o;
        return;
    }
    __shared__ bf16 T[64 * 65];
    if (bx < 2816) {
        int id = bx - 2048;
        int kt = id & 15, ph = id >> 4;
        int p = ph >> 4, h = ph & 15;
        const float* Wp = (p == 0) ? WQ : (p == 1) ? WK : WV;
        const float* src = Wp + ((size_t)h * DM + (size_t)kt * 64) * DH;
        for (int i = 0; i < 4; i++) {
            int c = t + 256 * i;
            int r = c >> 4;
            int col = (c & 15) * 4;
            float4 v = *(const float4*)&src[r * 64 + col];
            T[(col + 0) * 65 + r] = (bf16)v.x;
            T[(col + 1) * 65 + r] = (bf16)v.y;
            T[(col + 2) * 65 + r] = (bf16)v.z;
            T[(col + 3) * 65 + r] = (bf16)v.w;
        }
        __syncthreads();
        bf16* dst = wT + (size_t)ph * 64 * DM + (size_t)kt * 64;
        for (int i = 0; i < 2; i++) {
            int c = t + 256 * i;
            int e = c >> 3;
            int k0 = (c & 7) * 8;
            bf16x8 o;
            for (int j = 0; j < 8; j++) o[j] = T[e * 65 + k0 + j];
            *(bf16x8*)&dst[(size_t)e * DM + k0] = o;
        }
    } else {
        int id = bx - 2816;
        int ht = id & 15, dt = id >> 4;
        for (int i = 0; i < 4; i++) {
            int c = t + 256 * i;
            int r = c >> 4;
            int col = (c & 15) * 4;
            float4 v = *(const float4*)&WO[((size_t)(ht * 64 + r)) * DM + dt * 64 + col];
            T[(col + 0) * 65 + r] = (bf16)v.x;
            T[(col + 1) * 65 + r] = (bf16)v.y;
            T[(col + 2) * 65 + r] = (bf16)v.z;
            T[(col + 3) * 65 + r] = (bf16)v.w;
        }
        __syncthreads();
        for (int i = 0; i < 2; i++) {
            int c = t + 256 * i;
            int d = c >> 3;
            int h0 = (c & 7) * 8;
            bf16x8 o;
            for (int j = 0; j < 8; j++) o[j] = T[d * 65 + h0 + j];
            *(bf16x8*)&woT[((size_t)(dt * 64 + d)) * DM + ht * 64 + h0] = o;
        }
    }
}

// ---------------------------------------------------------------------------
// K1: QKV projection — R10: 256x192 tile over the FLAT 3072-row W_qkv
// (wT's [p][he][k] layout IS flat [3072][1024]). grid (16 mt, 16 nt) = 256
// blocks = 100% CU coverage (vs R7's 192/256), natural xcd = mt%8 keeps the
// A-panel locality R9 proved matters. Pipeline identical to R7's 256-row
// 8-wave body: BK=32, ring-4 (4 x 28KB = 112KB), stage 3 ahead, counted
// vmcnt + raw s_barrier, setprio, XOR swizzle + pre-swizzled global source.
// B staging is 12KB/step: all threads 8KB + waves 0-3 the last 4KB ->
// per-wave FIFO asymmetric: waves 0-3 vmcnt(8), waves 4-7 vmcnt(6).
// Per-output K-accumulation order identical to R7 -> bit-identical results.
// ---------------------------------------------------------------------------
__global__ __launch_bounds__(512, 2) void k_qkv(const bf16* __restrict__ xb,
                                                const bf16* __restrict__ wT,
                                                const float* __restrict__ bQ,
                                                const float* __restrict__ bK,
                                                const float* __restrict__ bV,
                                                bf16* __restrict__ Qb,
                                                bf16* __restrict__ Kb,
                                                bf16* __restrict__ VTf) {
    int mt = blockIdx.x, nt = blockIdx.y;
    __shared__ __align__(16) char sm[114688];   // 4 slots x (A 16KB | B 12KB)
    int t = threadIdx.x;
    int lane = t & 63, w = t >> 6;
    int l15 = lane & 15, quad = lane >> 4;
    int wr = w >> 2, wc = w & 3;               // 2M x 4N wave grid
    int m0 = mt * 256;
    int n0 = nt * 192;                          // flat he3 base

    // ---- pre-swizzled global sources (phys P -> logical L), per region ----
    int P0 = t * 16;
    int L0 = P0 ^ (((P0 >> 7) & 3) << 4);
    int row0 = L0 >> 6, kc0 = (L0 >> 4) & 3;    // rows 0..127
    int P1 = 8192 + t * 16;
    int L1 = P1 ^ (((P1 >> 7) & 3) << 4);
    int row1 = L1 >> 6, kc1 = (L1 >> 4) & 3;    // rows 128..255 (B: t<256 -> 128..191)
    const bf16* gA0 = xb + (size_t)(m0 + row0) * DM + kc0 * 8;
    const bf16* gA1 = xb + (size_t)(m0 + row1) * DM + kc1 * 8;
    const bf16* gB0 = wT + (size_t)(n0 + row0) * DM + kc0 * 8;
    const bf16* gB1 = wT + (size_t)(n0 + row1) * DM + kc1 * 8;   // valid t<256

    auto stage = [&](int ts, bool bsel) {
        char* sb = sm + (ts & 3) * 28672;
        int ko = ts * 32;   // 32 k-elements per step
        if (!bsel) {
            gld16(sb + w * 1024, gA0 + ko);
            gld16(sb + 8192 + w * 1024, gA1 + ko);
        } else {
            gld16(sb + 16384 + w * 1024, gB0 + ko);
            if (w < 4) gld16(sb + 16384 + 8192 + w * 1024, gB1 + ko);
        }
    };

    // ---- swizzled ds_read offsets (slot-relative, constant per thread) ----
    int aoff[8], boff[3];
#pragma unroll
    for (int mi = 0; mi < 8; mi++) {
        int row = wr * 128 + mi * 16 + l15;
        aoff[mi] = row * 64 + ((quad ^ ((row >> 1) & 3)) << 4);
    }
#pragma unroll
    for (int ni = 0; ni < 3; ni++) {
        int row = wc * 48 + ni * 16 + l15;      // 0..191
        boff[ni] = 16384 + row * 64 + ((quad ^ ((row >> 1) & 3)) << 4);
    }

    const f32x4 z4 = {0.f, 0.f, 0.f, 0.f};
    f32x4 acc[8][3];
#pragma unroll
    for (int mi = 0; mi < 8; mi++)
#pragma unroll
        for (int ni = 0; ni < 3; ni++) acc[mi][ni] = z4;

    auto kstep = [&](int tt, bool st) {
        const char* sb = sm + (tt & 3) * 28672;
        bf16x8 bfr[3], afr[4];
#pragma unroll
        for (int ni = 0; ni < 3; ni++) bfr[ni] = *(const bf16x8*)(sb + boff[ni]);
#pragma unroll
        for (int mi = 0; mi < 4; mi++) afr[mi] = *(const bf16x8*)(sb + aoff[mi]);
        if (st) stage(tt + 3, false);
        __builtin_amdgcn_s_setprio(1);
#pragma unroll
        for (int mi = 0; mi < 4; mi++)
#pragma unroll
            for (int ni = 0; ni < 3; ni++)
                acc[mi][ni] = MFMA16(afr[mi], bfr[ni], acc[mi][ni]);
        __builtin_amdgcn_s_setprio(0);
        bf16x8 afr2[4];
#pragma unroll
        for (int mi = 0; mi < 4; mi++) afr2[mi] = *(const bf16x8*)(sb + aoff[4 + mi]);
        if (st) stage(tt + 3, true);
        __builtin_amdgcn_s_setprio(1);
#pragma unroll
        for (int mi = 0; mi < 4; mi++)
#pragma unroll
            for (int ni = 0; ni < 3; ni++)
                acc[4 + mi][ni] = MFMA16(afr2[mi], bfr[ni], acc[4 + mi][ni]);
        __builtin_amdgcn_s_setprio(0);
    };

    // waits: waves 0-3 issue 4 loads/step, waves 4-7 issue 3 -> counted
    // vmcnt differs per wave (wave-uniform branch), barrier shared.
#define QKV_WAIT(N03, N47)                                              \
    do {                                                                \
        if (w < 4) asm volatile("s_waitcnt vmcnt(" #N03 ")" ::: "memory"); \
        else       asm volatile("s_waitcnt vmcnt(" #N47 ")" ::: "memory"); \
        asm volatile("s_barrier" ::: "memory");                         \
        __builtin_amdgcn_sched_barrier(0);                              \
    } while (0)

    // prologue: stage steps 0,1,2 (FIFO order step-major, A before B)
    stage(0, false); stage(0, true);
    stage(1, false); stage(1, true);
    stage(2, false); stage(2, true);

#pragma unroll 1
    for (int tt = 0; tt < 29; tt++) {
        QKV_WAIT(8, 6);     // step tt fully landed; newest 2 steps in flight
        kstep(tt, true);
    }
    QKV_WAIT(8, 6);
    kstep(29, false);
    QKV_WAIT(4, 3);
    kstep(30, false);
    QKV_WAIT(0, 0);
    kstep(31, false);
#undef QKV_WAIT

    // ---- epilogue: C row s = m0 + wr*128 + mi*16 + quad*4 + r,
    //      C col he3 = n0 + wc*48 + ni*16 + l15 (p/no uniform per ni) ----
    int b = mt >> 3;
#pragma unroll
    for (int ni = 0; ni < 3; ni++) {
        int he3 = n0 + wc * 48 + ni * 16 + l15;
        int p = he3 >> 10;
        int he = he3 & 1023;
        int h = he >> 6, e = he & 63;
        if (p < 2) {
            const float* bias = (p == 0) ? bQ : bK;
            bf16* dst = (p == 0) ? Qb : Kb;
            float scale = (p == 0) ? QSCALE : 1.0f;
            float bia = bias[he];
            size_t rb = (size_t)(b * NH + h) * SEQ * DH + e;
#pragma unroll
            for (int mi = 0; mi < 8; mi++)
#pragma unroll
                for (int r = 0; r < 4; r++) {
                    int s = ((m0 + wr * 128 + mi * 16 + quad * 4 + r) & 2047);
                    dst[rb + (size_t)s * DH] = (bf16)((acc[mi][ni][r] + bia) * scale);
                }
        } else {
            // paired-fragment V store (contract with k_attn preserved):
            // no = (he3>>4)&3 (16-col group within head), f = (mi>>1)*4+no,
            // slot (quad<<4)|l15, elem j = (mi&1)*4 + r
            int no = (he3 >> 4) & 3;
            float bia = bV[he];
#pragma unroll
            for (int mi = 0; mi < 8; mi++) {
                int kvl = (mt & 7) * 256 + wr * 128 + mi * 16;
                int kt = kvl >> 7;
                int f = (mi >> 1) * 4 + no;
                size_t base = (((size_t)(b * NH + h) * 16 + kt) * 16 + f) * 512
                              + (size_t)((quad << 4) | l15) * 8 + (mi & 1) * 4;
                bf16x4 o;
#pragma unroll
                for (int r = 0; r < 4; r++) o[r] = (bf16)(acc[mi][ni][r] + bia);
                *(bf16x4*)&VTf[base] = o;
            }
        }
    }
}

// ---------------------------------------------------------------------------
// K2: flash attention (R7 body, unchanged — 160.4us best). 48 KB LDS ->
// 3 blocks/CU. K dbuf + single V buf; split counted-vmcnt waits; setprio
// around QK and PV MFMA clusters. grid (32,16): xcd = bh%8 gives per-bh
// K/V L2 locality; y-pairing balances qt sums.
// ---------------------------------------------------------------------------
__global__ __launch_bounds__(512, 4) void k_attn(const bf16* __restrict__ Qb,
                                                 const bf16* __restrict__ Kb,
                                                 const bf16* __restrict__ VTf,
                                                 bf16* __restrict__ Zb) {
    int bh = blockIdx.x;
    int y = blockIdx.y;
    int qt = (y < 8) ? y : 23 - y;
    int h = bh & 15, b = bh >> 4;
    __shared__ __align__(16) bf16 Ks[2][16 * 512];   // 32 KB
    __shared__ __align__(16) bf16 Vs[16 * 512];      // 16 KB
    int t = threadIdx.x;
    int lane = t & 63, w = t >> 6;
    int l15 = lane & 15, quad = lane >> 4;

    const bf16* qbase = Qb + (size_t)bh * SEQ * DH;
    const bf16* kbase = Kb + (size_t)bh * SEQ * DH;
    const bf16* vfrag = VTf + (size_t)bh * 16 * 8192;

    int qr0 = qt * 128 + w * 16;
    bf16x8 aq[2];   // Q as B-operand: lane holds q=qr0+l15, e=ks*32+quad*8+j
    for (int ks = 0; ks < 2; ks++)
        aq[ks] = *(const bf16x8*)&qbase[(size_t)(qr0 + l15) * DH + ks * 32 + quad * 8];

    auto stageK = [&](int buf, int kt) {
        for (int i = 0; i < 2; i++) {
            int f = w * 2 + i;
            int ks = f >> 3, ni = f & 7;
            gld16(&Ks[buf][f * 512],
                  kbase + (size_t)(kt * 128 + ni * 16 + l15) * DH + ks * 32 + quad * 8);
        }
    };
    auto stageV = [&](int kt) {
        const bf16* vt = vfrag + (size_t)kt * 8192;
        for (int i = 0; i < 2; i++) {
            int f = w * 2 + i;
            gld16(&Vs[f * 512], vt + f * 512 + lane * 8);
        }
    };

    const bf16 one = (bf16)1.0f;
    const bf16x8 ones = {one, one, one, one, one, one, one, one};
    const f32x4 z4 = {0.f, 0.f, 0.f, 0.f};
    f32x4 acco[4], accd;
    for (int no = 0; no < 4; no++) acco[no] = z4;
    accd = z4;

    stageK(0, 0);

    for (int kt = 0; kt <= qt; kt++) {
        int buf = kt & 1;
        // K[kt] ready (only K outstanding; cover = prev QK+softmax+PV)
        asm volatile("s_waitcnt vmcnt(0)\n\ts_barrier" ::: "memory");
        __builtin_amdgcn_sched_barrier(0);
        stageV(kt);        // V[kt] lands during QK+softmax below
        if (kt < qt) stageK(buf ^ 1, kt + 1);
        const bf16* Kbuf = Ks[buf];

        // S^T = K x Q^T : lane holds q=l15, kv=ni*16+quad*4+r
        f32x4 accs[8];
        for (int ni = 0; ni < 8; ni++) accs[ni] = z4;
        __builtin_amdgcn_s_setprio(1);
        for (int ks = 0; ks < 2; ks++)
            for (int ni = 0; ni < 8; ni++) {
                bf16x8 ak = *(const bf16x8*)&Kbuf[(ks * 8 + ni) * 512 + lane * 8];
                accs[ni] = MFMA16(ak, aq[ks], accs[ni]);
            }
        __builtin_amdgcn_s_setprio(0);

        if (kt == qt) {   // causal mask on diagonal tile
            int ql = w * 16 + l15;
            for (int ni = 0; ni < 8; ni++) {
                int kvl = ni * 16 + quad * 4;
                for (int r = 0; r < 4; r++)
                    if (kvl + r > ql) accs[ni][r] = -1e30f;
            }
        }

        // P^T = exp2(S^T) in registers
        bf16x4 pt[8];
        for (int ni = 0; ni < 8; ni++)
            for (int r = 0; r < 4; r++)
                pt[ni][r] = (bf16)EXP2(accs[ni][r]);

        // V[kt] done (FIFO [V,V,K,K]); K[kt+1] may stay in flight through PV
        if (kt < qt) {
            asm volatile("s_waitcnt vmcnt(2)\n\ts_barrier" ::: "memory");
        } else {
            asm volatile("s_waitcnt vmcnt(0)\n\ts_barrier" ::: "memory");
        }
        __builtin_amdgcn_sched_barrier(0);

        // O += P(A) x V(B); V frags linear b128. ones-B -> per-lane denominator.
        __builtin_amdgcn_s_setprio(1);
        for (int p4 = 0; p4 < 4; p4++) {
            bf16x8 ap;
            for (int j = 0; j < 4; j++) {
                ap[j] = pt[2 * p4][j];
                ap[4 + j] = pt[2 * p4 + 1][j];
            }
            accd = MFMA16(ap, ones, accd);
            for (int no = 0; no < 4; no++) {
                bf16x8 bv = *(const bf16x8*)&Vs[(p4 * 4 + no) * 512 + lane * 8];
                acco[no] = MFMA16(ap, bv, acco[no]);
            }
        }
        __builtin_amdgcn_s_setprio(0);
    }

    // epilogue: O[q][e], per-lane denominator; 32B runs along e
    for (int r = 0; r < 4; r++) {
        float inv = 1.0f / accd[r];
        int q = qr0 + quad * 4 + r;
        size_t rowbase = ((size_t)b * SEQ + q) * DM + h * DH;
        for (int no = 0; no < 4; no++)
            Zb[rowbase + no * 16 + l15] = (bf16)(acco[no][r] * inv);
    }
}

// ---------------------------------------------------------------------------
// K3: out[s][d] = Zb @ woT + bO, 128x128 tile deep-pipeline (R7 body,
// unchanged). BK=32, ring-4 (64KB), stage 3 ahead, counted vmcnt(8),
// setprio, XOR swizzle + pre-swizzled global source. grid (32,8) = 256
// blocks; natural xcd = mt%8 keeps A(Zb)-panel locality.
// ---------------------------------------------------------------------------
__global__ __launch_bounds__(256, 2) void k_out(const bf16* __restrict__ Zb,
                                                const bf16* __restrict__ woT,
                                                const float* __restrict__ bO,
                                                float* __restrict__ out) {
    int mt = blockIdx.x, nt = blockIdx.y;
    __shared__ __align__(16) char sm[65536];   // 4 slots x (A 8KB | B 8KB)
    int t = threadIdx.x;
    int lane = t & 63, w = t >> 6;
    int l15 = lane & 15, quad = lane >> 4;
    int wr = w >> 1, wc = w & 1;               // 2M x 2N wave grid
    int m0 = mt * 128, n0 = nt * 128;

    // pre-swizzled global sources (phys P -> logical L), regions of 8KB
    int P0 = t * 16;
    int L0 = P0 ^ (((P0 >> 7) & 3) << 4);
    int row0 = L0 >> 6, kc0 = (L0 >> 4) & 3;
    int P1 = 4096 + t * 16;
    int L1 = P1 ^ (((P1 >> 7) & 3) << 4);
    int row1 = L1 >> 6, kc1 = (L1 >> 4) & 3;
    const bf16* gA0 = Zb + (size_t)(m0 + row0) * DM + kc0 * 8;
    const bf16* gA1 = Zb + (size_t)(m0 + row1) * DM + kc1 * 8;
    const bf16* gB0 = woT + (size_t)(n0 + row0) * DM + kc0 * 8;
    const bf16* gB1 = woT + (size_t)(n0 + row1) * DM + kc1 * 8;

    auto stage = [&](int ts) {
        char* sb = sm + (ts & 3) * 16384;
        int ko = ts * 32;
        gld16(sb + w * 1024, gA0 + ko);
        gld16(sb + 4096 + w * 1024, gA1 + ko);
        gld16(sb + 8192 + w * 1024, gB0 + ko);
        gld16(sb + 8192 + 4096 + w * 1024, gB1 + ko);
    };

    int aoff[4], boff[4];
#pragma unroll
    for (int mi = 0; mi < 4; mi++) {
        int row = wr * 64 + mi * 16 + l15;
        aoff[mi] = row * 64 + ((quad ^ ((row >> 1) & 3)) << 4);
    }
#pragma unroll
    for (int ni = 0; ni < 4; ni++) {
        int row = wc * 64 + ni * 16 + l15;
        boff[ni] = 8192 + row * 64 + ((quad ^ ((row >> 1) & 3)) << 4);
    }

    const f32x4 z4 = {0.f, 0.f, 0.f, 0.f};
    f32x4 acc[4][4];
#pragma unroll
    for (int mi = 0; mi < 4; mi++)
#pragma unroll
        for (int ni = 0; ni < 4; ni++) acc[mi][ni] = z4;

    auto kstep = [&](int tt, bool st) {
        const char* sb = sm + (tt & 3) * 16384;
        bf16x8 bfr[4], afr[4];
#pragma unroll
        for (int ni = 0; ni < 4; ni++) bfr[ni] = *(const bf16x8*)(sb + boff[ni]);
#pragma unroll
        for (int mi = 0; mi < 4; mi++) afr[mi] = *(const bf16x8*)(sb + aoff[mi]);
        if (st) stage(tt + 3);
        __builtin_amdgcn_s_setprio(1);
#pragma unroll
        for (int mi = 0; mi < 4; mi++)
#pragma unroll
            for (int ni = 0; ni < 4; ni++)
                acc[mi][ni] = MFMA16(afr[mi], bfr[ni], acc[mi][ni]);
        __builtin_amdgcn_s_setprio(0);
    };

    stage(0); stage(1); stage(2);   // 12 loads in flight

#pragma unroll 1
    for (int tt = 0; tt < 29; tt++) {
        // step tt's 4 loads are older than the newest 8 (steps tt+1,tt+2)
        asm volatile("s_waitcnt vmcnt(8)\n\ts_barrier" ::: "memory");
        __builtin_amdgcn_sched_barrier(0);
        kstep(tt, true);
    }
    asm volatile("s_waitcnt vmcnt(8)\n\ts_barrier" ::: "memory");
    __builtin_amdgcn_sched_barrier(0);
    kstep(29, false);
    asm volatile("s_waitcnt vmcnt(4)\n\ts_barrier" ::: "memory");
    __builtin_amdgcn_sched_barrier(0);
    kstep(30, false);
    asm volatile("s_waitcnt vmcnt(0)\n\ts_barrier" ::: "memory");
    __builtin_amdgcn_sched_barrier(0);
    kstep(31, false);

    // epilogue: s = m0 + wr*64 + mi*16 + quad*4 + r, d = n0 + wc*64 + ni*16 + l15
#pragma unroll
    for (int ni = 0; ni < 4; ni++) {
        int d = n0 + wc * 64 + ni * 16 + l15;
        float bia = bO[d];
#pragma unroll
        for (int mi = 0; mi < 4; mi++)
#pragma unroll
            for (int r = 0; r < 4; r++) {
                int s = m0 + wr * 64 + mi * 16 + quad * 4 + r;
                out[(size_t)s * DM + d] = acc[mi][ni][r] + bia;
            }
    }
}

// ---------------------------------------------------------------------------
extern "C" void kernel_launch(void* const* d_in, const int* in_sizes, int n_in,
                              void* d_out, int out_size, void* d_ws, size_t ws_size,
                              hipStream_t stream) {
    const float* x  = (const float*)d_in[0];
    const float* WQ = (const float*)d_in[1];
    const float* WK = (const float*)d_in[2];
    const float* WV = (const float*)d_in[3];
    const float* WO = (const float*)d_in[4];
    const float* bQ = (const float*)d_in[5];
    const float* bK = (const float*)d_in[6];
    const float* bV = (const float*)d_in[7];
    const float* bO = (const float*)d_in[8];
    float* out = (float*)d_out;

    char* w = (char*)d_ws;
    bf16* xb    = (bf16*)(w + 0);                      //  8 MB [4096][1024]
    bf16* wqkvT = (bf16*)(w + (8u << 20));             //  6 MB [p][he][k]
    bf16* woT   = (bf16*)(w + (14u << 20));            //  2 MB [d][he]
    bf16* Qb    = (bf16*)(w + (16u << 20));            //  8 MB [b][h][s][e]
    bf16* Kb    = (bf16*)(w + (24u << 20));            //  8 MB [b][h][s][e]
    bf16* VTf   = (bf16*)(w + (32u << 20));            //  8 MB [bh][kt][16][512]
    bf16* Zb    = (bf16*)(w + (40u << 20));            //  8 MB [b][s][h*64+e]

    k_prep<<<3072, 256, 0, stream>>>(x, WQ, WK, WV, WO, xb, wqkvT, woT);
    k_qkv<<<dim3(16, 16), 512, 0, stream>>>(xb, wqkvT, bQ, bK, bV, Qb, Kb, VTf);
    k_attn<<<dim3(32, 16), 512, 0, stream>>>(Qb, Kb, VTf, Zb);
    k_out<<<dim3(32, 8), 256, 0, stream>>>(Zb, woT, bO, out);
}